// Round 1
// 985.417 us; speedup vs baseline: 1.6198x; 1.6198x over previous
//
#include <hip/hip_runtime.h>
#include <math.h>

#define NB 8
#define NL 4096
#define NDIM 512
#define NS 32
#define NTOP 8
#define FEPS 1e-8f
#define NM (NB*NL)   // 32768 tokens

typedef unsigned short u16;
typedef unsigned int u32;
typedef __attribute__((ext_vector_type(8))) __bf16 bf16x8;
typedef __attribute__((ext_vector_type(4))) float f32x4;

// ---------------- K1: phase + avg magnitude per token ----------------
__global__ __launch_bounds__(256) void k_phase(
    const float4* __restrict__ z4, const float2* __restrict__ wr2,
    const float2* __restrict__ wi2, float* __restrict__ phase,
    float* __restrict__ avgmag) {
  int lane = threadIdx.x & 63;
  int m = blockIdx.x * 4 + (threadIdx.x >> 6);
  const float4* row = z4 + (size_t)m * 256;   // 256 float4 per token row
  float pr = 0.f, pi = 0.f, ms = 0.f;
#pragma unroll
  for (int j = 0; j < 4; j++) {
    int idx = lane + 64 * j;                  // covers d = 2*idx, 2*idx+1
    float4 v = row[idx];
    float2 wr = wr2[idx], wi = wi2[idx];
    pr += v.x * wr.x - v.y * wi.x + v.z * wr.y - v.w * wi.y;
    pi += v.x * wi.x + v.y * wr.x + v.z * wi.y + v.w * wr.y;
    ms += sqrtf(v.x * v.x + v.y * v.y + FEPS) + sqrtf(v.z * v.z + v.w * v.w + FEPS);
  }
#pragma unroll
  for (int off = 32; off >= 1; off >>= 1) {
    pr += __shfl_xor(pr, off);
    pi += __shfl_xor(pi, off);
    ms += __shfl_xor(ms, off);
  }
  if (lane == 0) {
    phase[m] = sqrtf(pr * pr + pi * pi + FEPS);
    avgmag[m] = ms * (1.0f / 512.0f);
  }
}

// ---------------- K2: salience + run scan (one block per batch row) ----------------
__global__ __launch_bounds__(256) void k_scan(
    const float* __restrict__ phase, const float* __restrict__ avgmag,
    const float* __restrict__ bias_p, const float* __restrict__ ns_p,
    float* __restrict__ salO, int* __restrict__ estart, int* __restrict__ eend) {
  __shared__ float am[NL];
  __shared__ int abv[NL];
  __shared__ int cnt[256];
  int b = blockIdx.x, t = threadIdx.x;
  size_t gb = (size_t)b * NL;
  if (t < NS) { estart[b * NS + t] = -1; eend[b * NS + t] = -1; }
  for (int i = t; i < NL; i += 256) am[i] = avgmag[gb + i];
  __syncthreads();
  float bias = bias_p[0], ns = ns_p[0];
  for (int i = t; i < NL; i += 256) {
    float lm = am[i];
    if (i >= 2) lm += am[i - 2];
    if (i >= 1) lm += am[i - 1];
    if (i <= NL - 2) lm += am[i + 1];
    if (i <= NL - 3) lm += am[i + 2];
    lm *= 0.2f;
    float x = phase[gb + i] + (am[i] - lm) * ns + bias;
    float s = 1.0f / (1.0f + expf(-x));
    salO[gb + i] = s;
    abv[i] = (s > 0.5f) ? 1 : 0;
  }
  __syncthreads();
  // count starts in each thread's 16-token chunk
  int c = 0, l0 = t * 16;
  for (int j = 0; j < 16; j++) {
    int l = l0 + j;
    int a = abv[l];
    int p = (l == 0) ? 0 : abv[l - 1];
    c += (a && !p) ? 1 : 0;
  }
  cnt[t] = c;
  __syncthreads();
  for (int off = 1; off < 256; off <<= 1) {   // inclusive Hillis-Steele scan
    int v = (t >= off) ? cnt[t - off] : 0;
    __syncthreads();
    cnt[t] += v;
    __syncthreads();
  }
  c = (t > 0) ? cnt[t - 1] : 0;
  for (int j = 0; j < 16; j++) {
    int l = l0 + j;
    int a = abv[l];
    int p = (l == 0) ? 0 : abv[l - 1];
    int st = (a && !p) ? 1 : 0;
    c += st;
    int ev = c - 1;
    if (a && ev >= 0 && ev < NS) {
      if (st) estart[b * NS + ev] = l;
      int nxt = (l == NL - 1) ? 0 : abv[l + 1];
      if (!nxt) eend[b * NS + ev] = l + 1;
    }
  }
}

// ---------------- K3: event accumulation (one block per (b,s)) ----------------
__global__ __launch_bounds__(256) void k_event(
    const float4* __restrict__ z4, const float* __restrict__ salO,
    const int* __restrict__ estart, const int* __restrict__ eend,
    float4* __restrict__ evec4, float* __restrict__ emask) {
  int i = blockIdx.x;            // b*NS + s
  int b = i >> 5;
  int t = threadIdx.x;
  int st = estart[i];
  int en = (st >= 0) ? eend[i] : 0;
  if (st < 0) st = 0;
  float4 acc = {0.f, 0.f, 0.f, 0.f};
  float den = 0.f;
  for (int l = st; l < en; l++) {
    float w = salO[(size_t)b * NL + l];
    float4 v = z4[((size_t)b * NL + l) * 256 + t];
    acc.x += w * v.x; acc.y += w * v.y; acc.z += w * v.z; acc.w += w * v.w;
    den += w;
  }
  float inv = 1.0f / fmaxf(den, FEPS);
  float4 o = {acc.x * inv, acc.y * inv, acc.z * inv, acc.w * inv};
  evec4[(size_t)i * 256 + t] = o;
  if (t == 0) emask[i] = (den > 0.f) ? 1.0f : 0.0f;
}

// ---------------- K4: event keys/values + blend + kmag + new_mask ----------------
__global__ __launch_bounds__(256) void k_kv(
    const float* __restrict__ evec, const float* __restrict__ emask,
    const float* __restrict__ Wekr, const float* __restrict__ Weki,
    const float* __restrict__ Wevr, const float* __restrict__ Wevi,
    const float* __restrict__ slotK, const float* __restrict__ slotV,
    const float* __restrict__ slotM, float* __restrict__ newK,
    float* __restrict__ newV, float* __restrict__ newM,
    float* __restrict__ kmag) {
  __shared__ float ev[1024];
  __shared__ float red[256];
  int i = blockIdx.x, t = threadIdx.x;
  for (int j = t; j < 1024; j += 256) ev[j] = evec[(size_t)i * 1024 + j];
  __syncthreads();
  int d0 = t, d1 = t + 256;
  float kr0 = 0, ki0 = 0, kr1 = 0, ki1 = 0;
  float vr0 = 0, vi0 = 0, vr1 = 0, vi1 = 0;
  for (int k = 0; k < NDIM; k++) {
    float er = ev[2 * k], ei = ev[2 * k + 1];
    int o = k * NDIM;
    float a0 = Wekr[o + d0], a1 = Wekr[o + d1];
    float b0 = Weki[o + d0], b1 = Weki[o + d1];
    kr0 += er * a0 - ei * b0; ki0 += er * b0 + ei * a0;
    kr1 += er * a1 - ei * b1; ki1 += er * b1 + ei * a1;
    a0 = Wevr[o + d0]; a1 = Wevr[o + d1];
    b0 = Wevi[o + d0]; b1 = Wevi[o + d1];
    vr0 += er * a0 - ei * b0; vi0 += er * b0 + ei * a0;
    vr1 += er * a1 - ei * b1; vi1 += er * b1 + ei * a1;
  }
  float m = emask[i];
  const float2* sk = (const float2*)slotK + (size_t)i * NDIM;
  const float2* sv = (const float2*)slotV + (size_t)i * NDIM;
  float2 s0 = sk[d0], s1 = sk[d1], t0 = sv[d0], t1 = sv[d1];
  float nkr0 = (m > 0.f) ? kr0 : s0.x, nki0 = (m > 0.f) ? ki0 : s0.y;
  float nkr1 = (m > 0.f) ? kr1 : s1.x, nki1 = (m > 0.f) ? ki1 : s1.y;
  float nvr0 = (m > 0.f) ? vr0 : t0.x, nvi0 = (m > 0.f) ? vi0 : t0.y;
  float nvr1 = (m > 0.f) ? vr1 : t1.x, nvi1 = (m > 0.f) ? vi1 : t1.y;
  float2* nk = (float2*)newK + (size_t)i * NDIM;
  float2* nv = (float2*)newV + (size_t)i * NDIM;
  nk[d0] = {nkr0, nki0}; nk[d1] = {nkr1, nki1};
  nv[d0] = {nvr0, nvi0}; nv[d1] = {nvr1, nvi1};
  red[t] = nkr0 * nkr0 + nki0 * nki0 + nkr1 * nkr1 + nki1 * nki1;
  __syncthreads();
  for (int off = 128; off >= 1; off >>= 1) {
    if (t < off) red[t] += red[t + off];
    __syncthreads();
  }
  if (t == 0) {
    kmag[i] = sqrtf(red[0] + FEPS);
    newM[i] = fminf(slotM[i] + m, 1.0f);
  }
}

// ---------------- K5a: build transposed composite B in bf16 ----------------
// BT[n][k] = Bcomp[k][n], Bcomp = [[Wr, Wi], [-Wi, Wr]]  (1024x1024)
__device__ inline u16 f2bf_rne(float f) {
  u32 u = __float_as_uint(f);
  u32 r = (u + 0x7fffu + ((u >> 16) & 1u)) >> 16;
  return (u16)r;
}

__global__ __launch_bounds__(256) void k_wbf16(
    const float* __restrict__ Wr, const float* __restrict__ Wi,
    u16* __restrict__ BT) {
  __shared__ float tile[64][65];
  int bx = blockIdx.x & 15;   // k-tile
  int by = blockIdx.x >> 4;   // n-tile
  int k0 = bx * 64, n0 = by * 64;
  int t = threadIdx.x;
  int c = t & 63, r0 = t >> 6;
  const float* src;
  float sgn = 1.f;
  int kk0 = k0 & 511, nn0 = n0 & 511;
  if (k0 < 512) {
    src = (n0 < 512) ? Wr : Wi;
  } else {
    if (n0 < 512) { src = Wi; sgn = -1.f; }
    else          { src = Wr; }
  }
  for (int j = r0; j < 64; j += 4)
    tile[j][c] = sgn * src[(size_t)(kk0 + j) * 512 + nn0 + c];
  __syncthreads();
  for (int j = r0; j < 64; j += 4) {
    float v = tile[c][j];   // = Bcomp[k0+c][n0+j]
    BT[(size_t)(n0 + j) * 1024 + k0 + c] = f2bf_rne(v);
  }
}

// ---------------- K5b: qmag via bf16 MFMA GEMM with fused row-norm ----------------
// A = Zc composite (M x 1024, bf16 truncated from z on the fly)
// B = BT (bf16, pre-transposed [n][k])
// output: qpart[m][nt] = sum over that n-tile's 128 cols of Q[m][n]^2
__global__ __launch_bounds__(256) void k_qmag(
    const float2* __restrict__ z2, const u16* __restrict__ BT,
    float* __restrict__ qpart) {
  __shared__ __align__(16) u16 As[128 * 32];
  __shared__ __align__(16) u16 Bs[128 * 32];
  int bid = blockIdx.x;
  int work = (bid & 7) * 256 + (bid >> 3);   // XCD swizzle (2048 % 8 == 0)
  int mt = work >> 3, nt = work & 7;
  int m0 = mt * 128, n0 = nt * 128;
  int t = threadIdx.x;
  int lane = t & 63, w = t >> 6;
  int lrow = lane & 15, kg = lane >> 4;
  int arow = t >> 1, ak = (t & 1) * 16;

  f32x4 acc[2][8];
#pragma unroll
  for (int m = 0; m < 2; m++)
#pragma unroll
    for (int n = 0; n < 8; n++)
#pragma unroll
      for (int r = 0; r < 4; r++) acc[m][n][r] = 0.f;

  for (int kt = 0; kt < 1024; kt += 32) {
    int half = kt >> 9;
    int dd = kt & 511;
    {  // stage A: convert z (interleaved f32) -> bf16 composite tile [128][32]
      const float4* src = (const float4*)(z2 + (size_t)(m0 + arow) * 512 + dd + ak);
      u32 o[8];
#pragma unroll
      for (int q = 0; q < 8; q++) {
        float4 f = src[q];
        float e0 = half ? f.y : f.x;
        float e1 = half ? f.w : f.z;
        o[q] = (__float_as_uint(e1) & 0xffff0000u) | (__float_as_uint(e0) >> 16);
      }
      int4* dst = (int4*)&As[arow * 32 + ak];
      int4 w0; w0.x = (int)o[0]; w0.y = (int)o[1]; w0.z = (int)o[2]; w0.w = (int)o[3];
      int4 w1; w1.x = (int)o[4]; w1.y = (int)o[5]; w1.z = (int)o[6]; w1.w = (int)o[7];
      dst[0] = w0; dst[1] = w1;
    }
    {  // stage B: straight bf16 copy [128][32]
      const int4* src = (const int4*)(BT + (size_t)(n0 + arow) * 1024 + kt + ak);
      int4 b0 = src[0], b1 = src[1];
      int4* dst = (int4*)&Bs[arow * 32 + ak];
      dst[0] = b0; dst[1] = b1;
    }
    __syncthreads();
    bf16x8 af[2];
#pragma unroll
    for (int m = 0; m < 2; m++)
      af[m] = *(const bf16x8*)&As[(w * 32 + m * 16 + lrow) * 32 + kg * 8];
#pragma unroll
    for (int n = 0; n < 8; n++) {
      bf16x8 bfr = *(const bf16x8*)&Bs[(n * 16 + lrow) * 32 + kg * 8];
      acc[0][n] = __builtin_amdgcn_mfma_f32_16x16x32_bf16(af[0], bfr, acc[0][n], 0, 0, 0);
      acc[1][n] = __builtin_amdgcn_mfma_f32_16x16x32_bf16(af[1], bfr, acc[1][n], 0, 0, 0);
    }
    __syncthreads();
  }
  // epilogue: row sums of squares; C/D layout col=lane&15, row=(lane>>4)*4+reg
#pragma unroll
  for (int m = 0; m < 2; m++)
#pragma unroll
    for (int r = 0; r < 4; r++) {
      float s = 0.f;
#pragma unroll
      for (int n = 0; n < 8; n++) { float v = acc[m][n][r]; s += v * v; }
      s += __shfl_xor(s, 1); s += __shfl_xor(s, 2);
      s += __shfl_xor(s, 4); s += __shfl_xor(s, 8);
      if (lrow == 0)
        qpart[(size_t)(m0 + w * 32 + m * 16 + kg * 4 + r) * 8 + nt] = s;
    }
}

// ---------------- K6: g[b][s] = Bcomp @ khat  (fp32, one block per (b,s)) ----------------
// g[j]      = sum_n Wr[j][n]*kr[n] + Wi[j][n]*ki[n]        (j < 512)
// g[512+j]  = sum_n Wr[j][n]*ki[n] - Wi[j][n]*kr[n]
__global__ __launch_bounds__(256) void k_gvec(
    const float* __restrict__ newK, const float* __restrict__ Wr,
    const float* __restrict__ Wi, float* __restrict__ g) {
  __shared__ float kr[512], ki[512];
  int i = blockIdx.x, t = threadIdx.x;
  const float2* krow = (const float2*)newK + (size_t)i * 512;
  for (int j = t; j < 512; j += 256) { float2 v = krow[j]; kr[j] = v.x; ki[j] = v.y; }
  __syncthreads();
  float g0lo = 0, g0hi = 0, g1lo = 0, g1hi = 0;
  const float4* wr0 = (const float4*)(Wr + (size_t)t * 512);
  const float4* wi0 = (const float4*)(Wi + (size_t)t * 512);
  const float4* wr1 = (const float4*)(Wr + (size_t)(t + 256) * 512);
  const float4* wi1 = (const float4*)(Wi + (size_t)(t + 256) * 512);
  const float4* kr4 = (const float4*)kr;
  const float4* ki4 = (const float4*)ki;
  for (int n4 = 0; n4 < 128; n4++) {
    float4 a = wr0[n4], b = wi0[n4], c = wr1[n4], d = wi1[n4];
    float4 kk = kr4[n4], qq = ki4[n4];
    g0lo += a.x * kk.x + b.x * qq.x + a.y * kk.y + b.y * qq.y
          + a.z * kk.z + b.z * qq.z + a.w * kk.w + b.w * qq.w;
    g0hi += a.x * qq.x - b.x * kk.x + a.y * qq.y - b.y * kk.y
          + a.z * qq.z - b.z * kk.z + a.w * qq.w - b.w * kk.w;
    g1lo += c.x * kk.x + d.x * qq.x + c.y * kk.y + d.y * qq.y
          + c.z * kk.z + d.z * qq.z + c.w * kk.w + d.w * qq.w;
    g1hi += c.x * qq.x - d.x * kk.x + c.y * qq.y - d.y * kk.y
          + c.z * qq.z - d.z * kk.z + c.w * qq.w - d.w * kk.w;
  }
  float* go = g + (size_t)i * 1024;
  go[t] = g0lo;
  go[t + 256] = g1lo;
  go[512 + t] = g0hi;
  go[768 + t] = g1hi;
}

// ---------------- K7: dot[m][s] = Zc[m] . g[b][s]  (fp32, LDS-staged g) ----------------
__global__ __launch_bounds__(256) void k_dot(
    const float4* __restrict__ z4, const float* __restrict__ g,
    float* __restrict__ dotb) {
  __shared__ float gs[16 * 1024];    // 64 KB: 16 slots per pass
  int blk = blockIdx.x;
  int b = blk >> 5, chunk = blk & 31;
  int t = threadIdx.x, lane = t & 63, w = t >> 6;
  int mbase = b * 4096 + chunk * 128 + w * 32;
  for (int p = 0; p < 2; p++) {
    __syncthreads();
    {
      const float4* gsrc = (const float4*)(g + (size_t)b * 32768 + p * 16384);
      float4* gd = (float4*)gs;
      for (int j = t; j < 4096; j += 256) gd[j] = gsrc[j];
    }
    __syncthreads();
    for (int it = 0; it < 8; it++) {
      int m = mbase + it * 4;
      float4 zr0[4], zr1[4], zr2[4], zr3[4];
#pragma unroll
      for (int jj = 0; jj < 4; jj++) {
        zr0[jj] = z4[(size_t)(m + 0) * 256 + lane + 64 * jj];
        zr1[jj] = z4[(size_t)(m + 1) * 256 + lane + 64 * jj];
        zr2[jj] = z4[(size_t)(m + 2) * 256 + lane + 64 * jj];
        zr3[jj] = z4[(size_t)(m + 3) * 256 + lane + 64 * jj];
      }
      float myd0 = 0, myd1 = 0, myd2 = 0, myd3 = 0;
      for (int s = 0; s < 16; s++) {
        float p0 = 0, p1 = 0, p2 = 0, p3 = 0;
        const float2* gl = (const float2*)(gs + s * 1024);
#pragma unroll
        for (int jj = 0; jj < 4; jj++) {
          int idx = lane + 64 * jj;
          float2 lo = gl[idx], hi = gl[256 + idx];
          p0 += zr0[jj].x * lo.x + zr0[jj].z * lo.y + zr0[jj].y * hi.x + zr0[jj].w * hi.y;
          p1 += zr1[jj].x * lo.x + zr1[jj].z * lo.y + zr1[jj].y * hi.x + zr1[jj].w * hi.y;
          p2 += zr2[jj].x * lo.x + zr2[jj].z * lo.y + zr2[jj].y * hi.x + zr2[jj].w * hi.y;
          p3 += zr3[jj].x * lo.x + zr3[jj].z * lo.y + zr3[jj].y * hi.x + zr3[jj].w * hi.y;
        }
#pragma unroll
        for (int off = 32; off >= 1; off >>= 1) {
          p0 += __shfl_xor(p0, off);
          p1 += __shfl_xor(p1, off);
          p2 += __shfl_xor(p2, off);
          p3 += __shfl_xor(p3, off);
        }
        if (lane == s) { myd0 = p0; myd1 = p1; myd2 = p2; myd3 = p3; }
      }
      if (lane < 16) {
        int sidx = p * 16 + lane;
        dotb[(size_t)(m + 0) * 32 + sidx] = myd0;
        dotb[(size_t)(m + 1) * 32 + sidx] = myd1;
        dotb[(size_t)(m + 2) * 32 + sidx] = myd2;
        dotb[(size_t)(m + 3) * 32 + sidx] = myd3;
      }
    }
  }
}

// ---------------- K8: attention tail, one wave per token (no Q, no K reads) ----------------
__global__ __launch_bounds__(256) void k_attn2(
    const float* __restrict__ dotb, const float* __restrict__ qpart,
    const float* __restrict__ newV, const float* __restrict__ newM,
    const float* __restrict__ kmag, const float* __restrict__ gain,
    float* __restrict__ out0) {
  int lane = threadIdx.x & 63;
  int m = blockIdx.x * 4 + (threadIdx.x >> 6);
  int b = m >> 12;
  const float4* qp = (const float4*)(qpart + (size_t)m * 8);
  float4 q0 = qp[0], q1 = qp[1];
  float qs = q0.x + q0.y + q0.z + q0.w + q1.x + q1.y + q1.z + q1.w;
  float qmag = sqrtf(qs + FEPS);

  int s = lane & 31;
  float dot = dotb[(size_t)m * 32 + s];
  float km = kmag[b * NS + s];
  float sc = dot / (qmag * km + FEPS);
  if (newM[b * NS + s] == 0.0f) sc = -1.0e9f;
  float myscore = sc;

  // top-8, stable (lower index wins ties), like lax.top_k
  float topv[NTOP];
  int topi[NTOP];
#pragma unroll
  for (int it = 0; it < NTOP; it++) {
    float val = myscore;
    int idx = lane & 31;
#pragma unroll
    for (int off = 32; off >= 1; off >>= 1) {
      float ov = __shfl_xor(val, off);
      int oi = __shfl_xor(idx, off);
      if (ov > val || (ov == val && oi < idx)) { val = ov; idx = oi; }
    }
    topv[it] = val;
    topi[it] = idx;
    if ((lane & 31) == idx) myscore = -3.0e38f;
  }
  float mx = topv[0];
  float w[NTOP], wsum = 0.f;
#pragma unroll
  for (int it = 0; it < NTOP; it++) { w[it] = expf(topv[it] - mx); wsum += w[it]; }
  float inv = 1.0f / wsum;

  const float2* V2p = (const float2*)newV + (size_t)b * NS * NDIM;
  float vr[8], vi[8];
#pragma unroll
  for (int j = 0; j < 8; j++) { vr[j] = 0.f; vi[j] = 0.f; }
#pragma unroll
  for (int it = 0; it < NTOP; it++) {
    float a = w[it] * inv;
    const float2* vrow = V2p + (size_t)topi[it] * NDIM;
#pragma unroll
    for (int j = 0; j < 8; j++) {
      float2 v = vrow[lane + 64 * j];
      vr[j] += a * v.x;
      vi[j] += a * v.y;
    }
  }
  float r2 = 0.f;
#pragma unroll
  for (int j = 0; j < 8; j++) r2 += vr[j] * vr[j] + vi[j] * vi[j];
#pragma unroll
  for (int off = 32; off >= 1; off >>= 1) r2 += __shfl_xor(r2, off);
  float rinv = 1.0f / sqrtf(r2 * (1.0f / 512.0f) + FEPS);

  float2* orow = (float2*)out0 + (size_t)m * NDIM;
#pragma unroll
  for (int j = 0; j < 8; j++) {
    int d = lane + 64 * j;
    float g = gain[d] * rinv;
    orow[d] = {vr[j] * g, vi[j] * g};
  }
}

extern "C" void kernel_launch(void* const* d_in, const int* in_sizes, int n_in,
                              void* d_out, int out_size, void* d_ws, size_t ws_size,
                              hipStream_t stream) {
  const float* z      = (const float*)d_in[0];
  const float* slotK  = (const float*)d_in[1];
  const float* slotV  = (const float*)d_in[2];
  const float* slotM  = (const float*)d_in[3];
  const float* Wsr    = (const float*)d_in[4];
  const float* Wsi    = (const float*)d_in[5];
  const float* sbias  = (const float*)d_in[6];
  const float* nscale = (const float*)d_in[7];
  const float* Wekr   = (const float*)d_in[8];
  const float* Weki   = (const float*)d_in[9];
  const float* Wevr   = (const float*)d_in[10];
  const float* Wevi   = (const float*)d_in[11];
  const float* Wrqr   = (const float*)d_in[12];
  const float* Wrqi   = (const float*)d_in[13];
  const float* gain   = (const float*)d_in[14];

  float* out = (float*)d_out;
  float* out0 = out;                       // (B,L,DIM,2)
  float* newK = out + 33554432;            // (B,S,DIM,2)
  float* newV = newK + 262144;
  float* newM = newV + 262144;             // (B,S)
  float* salO = newM + 256;                // (B,L)

  float* ws = (float*)d_ws;
  float* phaseb = ws;                      // 32768
  float* avgmgb = phaseb + NM;             // 32768
  float* evec   = avgmgb + NM;             // 262144
  float* emask  = evec + 262144;           // 256
  float* kmagb  = emask + 256;             // 256
  float* gvec   = kmagb + 256;             // 262144  (B,S,1024)
  float* dotb   = gvec + 262144;           // 1048576 (M,32)
  float* qpart  = dotb + 1048576;          // 262144  (M,8)
  int* estart   = (int*)(qpart + 262144);
  int* eend     = estart + 256;
  u16* BT       = (u16*)(eend + 256);      // 1024*1024 bf16

  k_wbf16<<<256, 256, 0, stream>>>(Wrqr, Wrqi, BT);
  k_phase<<<NM / 4, 256, 0, stream>>>((const float4*)z, (const float2*)Wsr,
                                      (const float2*)Wsi, phaseb, avgmgb);
  k_scan<<<NB, 256, 0, stream>>>(phaseb, avgmgb, sbias, nscale, salO, estart, eend);
  k_event<<<NB * NS, 256, 0, stream>>>((const float4*)z, salO, estart, eend,
                                       (float4*)evec, emask);
  k_kv<<<NB * NS, 256, 0, stream>>>(evec, emask, Wekr, Weki, Wevr, Wevi,
                                    slotK, slotV, slotM, newK, newV, newM, kmagb);
  k_qmag<<<2048, 256, 0, stream>>>((const float2*)z, BT, qpart);
  k_gvec<<<NB * NS, 256, 0, stream>>>(newK, Wrqr, Wrqi, gvec);
  k_dot<<<256, 256, 0, stream>>>((const float4*)z, gvec, dotb);
  k_attn2<<<NM / 4, 256, 0, stream>>>(dotb, qpart, newV, newM, kmagb, gain, out0);
}

// Round 2
// 772.093 us; speedup vs baseline: 2.0673x; 1.2763x over previous
//
#include <hip/hip_runtime.h>
#include <math.h>

#define NB 8
#define NL 4096
#define NDIM 512
#define NS 32
#define NTOP 8
#define FEPS 1e-8f
#define NM (NB*NL)   // 32768 tokens

typedef unsigned short u16;
typedef unsigned int u32;
typedef __attribute__((ext_vector_type(8))) __bf16 bf16x8;
typedef __attribute__((ext_vector_type(4))) float f32x4;

__device__ __forceinline__ u16 f2bf_rne(float f) {
  u32 u = __float_as_uint(f);
  u32 r = (u + 0x7fffu + ((u >> 16) & 1u)) >> 16;
  return (u16)r;
}

__device__ __forceinline__ void gload16(const u16* g, u16* l) {
  __builtin_amdgcn_global_load_lds(
      (const __attribute__((address_space(1))) u32*)(g),
      (__attribute__((address_space(3))) u32*)(l), 16, 0, 0);
}

// ---------------- K1: phase + avg magnitude + bf16 composite A ----------------
__global__ __launch_bounds__(256) void k_phase(
    const float4* __restrict__ z4, const float2* __restrict__ wr2,
    const float2* __restrict__ wi2, float* __restrict__ phase,
    float* __restrict__ avgmag, u16* __restrict__ A) {
  int lane = threadIdx.x & 63;
  int m = blockIdx.x * 4 + (threadIdx.x >> 6);
  const float4* row = z4 + (size_t)m * 256;   // 256 float4 per token row
  u16* arow = A + (size_t)m * 1024;
  float pr = 0.f, pi = 0.f, ms = 0.f;
#pragma unroll
  for (int j = 0; j < 4; j++) {
    int idx = lane + 64 * j;                  // covers d = 2*idx, 2*idx+1
    float4 v = row[idx];
    float2 wr = wr2[idx], wi = wi2[idx];
    pr += v.x * wr.x - v.y * wi.x + v.z * wr.y - v.w * wi.y;
    pi += v.x * wi.x + v.y * wr.x + v.z * wi.y + v.w * wr.y;
    ms += sqrtf(v.x * v.x + v.y * v.y + FEPS) + sqrtf(v.z * v.z + v.w * v.w + FEPS);
    // composite bf16 A row: [d<512]=zr, [512+d]=zi
    u32 zr_pk = ((u32)f2bf_rne(v.z) << 16) | (u32)f2bf_rne(v.x);
    u32 zi_pk = ((u32)f2bf_rne(v.w) << 16) | (u32)f2bf_rne(v.y);
    *(u32*)&arow[2 * idx] = zr_pk;
    *(u32*)&arow[512 + 2 * idx] = zi_pk;
  }
#pragma unroll
  for (int off = 32; off >= 1; off >>= 1) {
    pr += __shfl_xor(pr, off);
    pi += __shfl_xor(pi, off);
    ms += __shfl_xor(ms, off);
  }
  if (lane == 0) {
    phase[m] = sqrtf(pr * pr + pi * pi + FEPS);
    avgmag[m] = ms * (1.0f / 512.0f);
  }
}

// ---------------- K2: salience + run scan (one block per batch row) ----------------
__global__ __launch_bounds__(256) void k_scan(
    const float* __restrict__ phase, const float* __restrict__ avgmag,
    const float* __restrict__ bias_p, const float* __restrict__ ns_p,
    float* __restrict__ salO, int* __restrict__ estart, int* __restrict__ eend) {
  __shared__ float am[NL];
  __shared__ int abv[NL];
  __shared__ int cnt[256];
  int b = blockIdx.x, t = threadIdx.x;
  size_t gb = (size_t)b * NL;
  if (t < NS) { estart[b * NS + t] = -1; eend[b * NS + t] = -1; }
  for (int i = t; i < NL; i += 256) am[i] = avgmag[gb + i];
  __syncthreads();
  float bias = bias_p[0], ns = ns_p[0];
  for (int i = t; i < NL; i += 256) {
    float lm = am[i];
    if (i >= 2) lm += am[i - 2];
    if (i >= 1) lm += am[i - 1];
    if (i <= NL - 2) lm += am[i + 1];
    if (i <= NL - 3) lm += am[i + 2];
    lm *= 0.2f;
    float x = phase[gb + i] + (am[i] - lm) * ns + bias;
    float s = 1.0f / (1.0f + expf(-x));
    salO[gb + i] = s;
    abv[i] = (s > 0.5f) ? 1 : 0;
  }
  __syncthreads();
  // count starts in each thread's 16-token chunk
  int c = 0, l0 = t * 16;
  for (int j = 0; j < 16; j++) {
    int l = l0 + j;
    int a = abv[l];
    int p = (l == 0) ? 0 : abv[l - 1];
    c += (a && !p) ? 1 : 0;
  }
  cnt[t] = c;
  __syncthreads();
  for (int off = 1; off < 256; off <<= 1) {   // inclusive Hillis-Steele scan
    int v = (t >= off) ? cnt[t - off] : 0;
    __syncthreads();
    cnt[t] += v;
    __syncthreads();
  }
  c = (t > 0) ? cnt[t - 1] : 0;
  for (int j = 0; j < 16; j++) {
    int l = l0 + j;
    int a = abv[l];
    int p = (l == 0) ? 0 : abv[l - 1];
    int st = (a && !p) ? 1 : 0;
    c += st;
    int ev = c - 1;
    if (a && ev >= 0 && ev < NS) {
      if (st) estart[b * NS + ev] = l;
      int nxt = (l == NL - 1) ? 0 : abv[l + 1];
      if (!nxt) eend[b * NS + ev] = l + 1;
    }
  }
}

// ---------------- K3: event accumulation (one block per (b,s)) ----------------
__global__ __launch_bounds__(256) void k_event(
    const float4* __restrict__ z4, const float* __restrict__ salO,
    const int* __restrict__ estart, const int* __restrict__ eend,
    float4* __restrict__ evec4, float* __restrict__ emask) {
  int i = blockIdx.x;            // b*NS + s
  int b = i >> 5;
  int t = threadIdx.x;
  int st = estart[i];
  int en = (st >= 0) ? eend[i] : 0;
  if (st < 0) st = 0;
  float4 acc = {0.f, 0.f, 0.f, 0.f};
  float den = 0.f;
  for (int l = st; l < en; l++) {
    float w = salO[(size_t)b * NL + l];
    float4 v = z4[((size_t)b * NL + l) * 256 + t];
    acc.x += w * v.x; acc.y += w * v.y; acc.z += w * v.z; acc.w += w * v.w;
    den += w;
  }
  float inv = 1.0f / fmaxf(den, FEPS);
  float4 o = {acc.x * inv, acc.y * inv, acc.z * inv, acc.w * inv};
  evec4[(size_t)i * 256 + t] = o;
  if (t == 0) emask[i] = (den > 0.f) ? 1.0f : 0.0f;
}

// ---------------- K4: event keys/values + blend + kmag + new_mask ----------------
__global__ __launch_bounds__(256) void k_kv(
    const float* __restrict__ evec, const float* __restrict__ emask,
    const float* __restrict__ Wekr, const float* __restrict__ Weki,
    const float* __restrict__ Wevr, const float* __restrict__ Wevi,
    const float* __restrict__ slotK, const float* __restrict__ slotV,
    const float* __restrict__ slotM, float* __restrict__ newK,
    float* __restrict__ newV, float* __restrict__ newM,
    float* __restrict__ kmag) {
  __shared__ float ev[1024];
  __shared__ float red[256];
  int i = blockIdx.x, t = threadIdx.x;
  for (int j = t; j < 1024; j += 256) ev[j] = evec[(size_t)i * 1024 + j];
  __syncthreads();
  int d0 = t, d1 = t + 256;
  float kr0 = 0, ki0 = 0, kr1 = 0, ki1 = 0;
  float vr0 = 0, vi0 = 0, vr1 = 0, vi1 = 0;
  for (int k = 0; k < NDIM; k++) {
    float er = ev[2 * k], ei = ev[2 * k + 1];
    int o = k * NDIM;
    float a0 = Wekr[o + d0], a1 = Wekr[o + d1];
    float b0 = Weki[o + d0], b1 = Weki[o + d1];
    kr0 += er * a0 - ei * b0; ki0 += er * b0 + ei * a0;
    kr1 += er * a1 - ei * b1; ki1 += er * b1 + ei * a1;
    a0 = Wevr[o + d0]; a1 = Wevr[o + d1];
    b0 = Wevi[o + d0]; b1 = Wevi[o + d1];
    vr0 += er * a0 - ei * b0; vi0 += er * b0 + ei * a0;
    vr1 += er * a1 - ei * b1; vi1 += er * b1 + ei * a1;
  }
  float m = emask[i];
  const float2* sk = (const float2*)slotK + (size_t)i * NDIM;
  const float2* sv = (const float2*)slotV + (size_t)i * NDIM;
  float2 s0 = sk[d0], s1 = sk[d1], t0 = sv[d0], t1 = sv[d1];
  float nkr0 = (m > 0.f) ? kr0 : s0.x, nki0 = (m > 0.f) ? ki0 : s0.y;
  float nkr1 = (m > 0.f) ? kr1 : s1.x, nki1 = (m > 0.f) ? ki1 : s1.y;
  float nvr0 = (m > 0.f) ? vr0 : t0.x, nvi0 = (m > 0.f) ? vi0 : t0.y;
  float nvr1 = (m > 0.f) ? vr1 : t1.x, nvi1 = (m > 0.f) ? vi1 : t1.y;
  float2* nk = (float2*)newK + (size_t)i * NDIM;
  float2* nv = (float2*)newV + (size_t)i * NDIM;
  nk[d0] = {nkr0, nki0}; nk[d1] = {nkr1, nki1};
  nv[d0] = {nvr0, nvi0}; nv[d1] = {nvr1, nvi1};
  red[t] = nkr0 * nkr0 + nki0 * nki0 + nkr1 * nkr1 + nki1 * nki1;
  __syncthreads();
  for (int off = 128; off >= 1; off >>= 1) {
    if (t < off) red[t] += red[t + off];
    __syncthreads();
  }
  if (t == 0) {
    kmag[i] = sqrtf(red[0] + FEPS);
    newM[i] = fminf(slotM[i] + m, 1.0f);
  }
}

// ---------------- K5a: build transposed composite B in bf16 ----------------
// BT[n][k] = Bcomp[k][n], Bcomp = [[Wr, Wi], [-Wi, Wr]]  (1024x1024)
__global__ __launch_bounds__(256) void k_wbf16(
    const float* __restrict__ Wr, const float* __restrict__ Wi,
    u16* __restrict__ BT) {
  __shared__ float tile[64][65];
  int bx = blockIdx.x & 15;   // k-tile
  int by = blockIdx.x >> 4;   // n-tile
  int k0 = bx * 64, n0 = by * 64;
  int t = threadIdx.x;
  int c = t & 63, r0 = t >> 6;
  const float* src;
  float sgn = 1.f;
  int kk0 = k0 & 511, nn0 = n0 & 511;
  if (k0 < 512) {
    src = (n0 < 512) ? Wr : Wi;
  } else {
    if (n0 < 512) { src = Wi; sgn = -1.f; }
    else          { src = Wr; }
  }
  for (int j = r0; j < 64; j += 4)
    tile[j][c] = sgn * src[(size_t)(kk0 + j) * 512 + nn0 + c];
  __syncthreads();
  for (int j = r0; j < 64; j += 4) {
    float v = tile[c][j];   // = Bcomp[k0+c][n0+j]
    BT[(size_t)(n0 + j) * 1024 + k0 + c] = f2bf_rne(v);
  }
}

// ---------------- K5b: qmag via bf16 MFMA GEMM, m97 structure ----------------
// A (M x 1024 bf16, pre-converted), BT (1024 x 1024 bf16, [n][k])
// output: qpart[m][nt16] = partial row sums of Q^2 (16 partials per row)
__global__ __launch_bounds__(256) void k_qmag(
    const u16* __restrict__ A, const u16* __restrict__ BT,
    float* __restrict__ qpart) {
  __shared__ __align__(16) u16 As[128 * 32];
  __shared__ __align__(16) u16 Bs[128 * 32];
  int bid = blockIdx.x;
  int work = (bid & 7) * 256 + (bid >> 3);   // XCD swizzle (2048 % 8 == 0)
  int mt = work >> 3, nt = work & 7;
  int m0 = mt * 128, n0 = nt * 128;
  int t = threadIdx.x;
  int lane = t & 63, w = t >> 6;
  int wr = w >> 1, wc = w & 1;               // wave's 64x64 quadrant
  int lrow = lane & 15, kg = lane >> 4;
  // global_load_lds addressing: LDS byte = c*4096 + w*1024 + lane*16
  //   -> row = c*64 + w*16 + lane/4, k-col = (lane&3)*8
  int grow = w * 16 + (lane >> 2);
  int gcol = (lane & 3) * 8;
  const u16* gA = A  + (size_t)(m0 + grow) * 1024 + gcol;
  const u16* gB = BT + (size_t)(n0 + grow) * 1024 + gcol;
  u16* lA = As + w * 512;   // element offset: byte w*1024
  u16* lB = Bs + w * 512;

  f32x4 acc[4][4];
#pragma unroll
  for (int i = 0; i < 4; i++)
#pragma unroll
    for (int j = 0; j < 4; j++)
#pragma unroll
      for (int r = 0; r < 4; r++) acc[i][j][r] = 0.f;

  for (int kt = 0; kt < 1024; kt += 32) {
    gload16(gA + kt, lA);
    gload16(gA + 64 * 1024 + kt, lA + 2048);
    gload16(gB + kt, lB);
    gload16(gB + 64 * 1024 + kt, lB + 2048);
    __syncthreads();
    bf16x8 af[4], bfr[4];
#pragma unroll
    for (int i = 0; i < 4; i++)
      af[i] = *(const bf16x8*)&As[(wr * 64 + i * 16 + lrow) * 32 + kg * 8];
#pragma unroll
    for (int j = 0; j < 4; j++)
      bfr[j] = *(const bf16x8*)&Bs[(wc * 64 + j * 16 + lrow) * 32 + kg * 8];
#pragma unroll
    for (int i = 0; i < 4; i++)
#pragma unroll
      for (int j = 0; j < 4; j++)
        acc[i][j] = __builtin_amdgcn_mfma_f32_16x16x32_bf16(af[i], bfr[j], acc[i][j], 0, 0, 0);
    __syncthreads();
  }
  // epilogue: sum of squares over this wave's 64 cols; C/D: col=lane&15, row=kg*4+r
#pragma unroll
  for (int i = 0; i < 4; i++)
#pragma unroll
    for (int r = 0; r < 4; r++) {
      float s = 0.f;
#pragma unroll
      for (int j = 0; j < 4; j++) { float v = acc[i][j][r]; s += v * v; }
      s += __shfl_xor(s, 1); s += __shfl_xor(s, 2);
      s += __shfl_xor(s, 4); s += __shfl_xor(s, 8);
      if (lrow == 0)
        qpart[(size_t)(m0 + wr * 64 + i * 16 + kg * 4 + r) * 16 + nt * 2 + wc] = s;
    }
}

// ---------------- K6: g[b][s] = Bcomp @ khat  (fp32, two blocks per (b,s)) ----------------
__global__ __launch_bounds__(256) void k_gvec(
    const float* __restrict__ newK, const float* __restrict__ Wr,
    const float* __restrict__ Wi, float* __restrict__ g) {
  __shared__ float kr[512], ki[512];
  int blk = blockIdx.x;
  int i = blk >> 1, h = blk & 1;
  int t = threadIdx.x;
  const float2* krow = (const float2*)newK + (size_t)i * 512;
  for (int j = t; j < 512; j += 256) { float2 v = krow[j]; kr[j] = v.x; ki[j] = v.y; }
  __syncthreads();
  int j = t + h * 256;   // output row
  float glo = 0, ghi = 0;
  const float4* wr0 = (const float4*)(Wr + (size_t)j * 512);
  const float4* wi0 = (const float4*)(Wi + (size_t)j * 512);
  const float4* kr4 = (const float4*)kr;
  const float4* ki4 = (const float4*)ki;
  for (int n4 = 0; n4 < 128; n4++) {
    float4 a = wr0[n4], b = wi0[n4];
    float4 kk = kr4[n4], qq = ki4[n4];
    glo += a.x * kk.x + b.x * qq.x + a.y * kk.y + b.y * qq.y
         + a.z * kk.z + b.z * qq.z + a.w * kk.w + b.w * qq.w;
    ghi += a.x * qq.x - b.x * kk.x + a.y * qq.y - b.y * kk.y
         + a.z * qq.z - b.z * kk.z + a.w * qq.w - b.w * kk.w;
  }
  float* go = g + (size_t)i * 1024;
  go[j] = glo;
  go[512 + j] = ghi;
}

// ---------------- K7: dot[m][s] = Zc[m] . g[b][s]  (fp32, LDS-staged g) ----------------
__global__ __launch_bounds__(256) void k_dot(
    const float4* __restrict__ z4, const float* __restrict__ g,
    float* __restrict__ dotb) {
  __shared__ float gs[16 * 1024];    // 64 KB: 16 slots per pass
  int blk = blockIdx.x;              // 512 blocks: 64 tokens each
  int b = blk >> 6, chunk = blk & 63;
  int t = threadIdx.x, lane = t & 63, w = t >> 6;
  int mbase = b * 4096 + chunk * 64 + w * 16;
  for (int p = 0; p < 2; p++) {
    __syncthreads();
    {
      const float4* gsrc = (const float4*)(g + (size_t)b * 32768 + p * 16384);
      float4* gd = (float4*)gs;
      for (int j = t; j < 4096; j += 256) gd[j] = gsrc[j];
    }
    __syncthreads();
    for (int it = 0; it < 4; it++) {
      int m = mbase + it * 4;
      float4 zr0[4], zr1[4], zr2[4], zr3[4];
#pragma unroll
      for (int jj = 0; jj < 4; jj++) {
        zr0[jj] = z4[(size_t)(m + 0) * 256 + lane + 64 * jj];
        zr1[jj] = z4[(size_t)(m + 1) * 256 + lane + 64 * jj];
        zr2[jj] = z4[(size_t)(m + 2) * 256 + lane + 64 * jj];
        zr3[jj] = z4[(size_t)(m + 3) * 256 + lane + 64 * jj];
      }
      float myd0 = 0, myd1 = 0, myd2 = 0, myd3 = 0;
      for (int s = 0; s < 16; s++) {
        float p0 = 0, p1 = 0, p2 = 0, p3 = 0;
        const float2* gl = (const float2*)(gs + s * 1024);
#pragma unroll
        for (int jj = 0; jj < 4; jj++) {
          int idx = lane + 64 * jj;
          float2 lo = gl[idx], hi = gl[256 + idx];
          p0 += zr0[jj].x * lo.x + zr0[jj].z * lo.y + zr0[jj].y * hi.x + zr0[jj].w * hi.y;
          p1 += zr1[jj].x * lo.x + zr1[jj].z * lo.y + zr1[jj].y * hi.x + zr1[jj].w * hi.y;
          p2 += zr2[jj].x * lo.x + zr2[jj].z * lo.y + zr2[jj].y * hi.x + zr2[jj].w * hi.y;
          p3 += zr3[jj].x * lo.x + zr3[jj].z * lo.y + zr3[jj].y * hi.x + zr3[jj].w * hi.y;
        }
#pragma unroll
        for (int off = 32; off >= 1; off >>= 1) {
          p0 += __shfl_xor(p0, off);
          p1 += __shfl_xor(p1, off);
          p2 += __shfl_xor(p2, off);
          p3 += __shfl_xor(p3, off);
        }
        if (lane == s) { myd0 = p0; myd1 = p1; myd2 = p2; myd3 = p3; }
      }
      if (lane < 16) {
        int sidx = p * 16 + lane;
        dotb[(size_t)(m + 0) * 32 + sidx] = myd0;
        dotb[(size_t)(m + 1) * 32 + sidx] = myd1;
        dotb[(size_t)(m + 2) * 32 + sidx] = myd2;
        dotb[(size_t)(m + 3) * 32 + sidx] = myd3;
      }
    }
  }
}

// ---------------- K8: attention tail, one wave per token ----------------
__global__ __launch_bounds__(256) void k_attn2(
    const float* __restrict__ dotb, const float* __restrict__ qpart,
    const float* __restrict__ newV, const float* __restrict__ newM,
    const float* __restrict__ kmag, const float* __restrict__ gain,
    float* __restrict__ out0) {
  int lane = threadIdx.x & 63;
  int m = blockIdx.x * 4 + (threadIdx.x >> 6);
  int b = m >> 12;
  const float4* qp = (const float4*)(qpart + (size_t)m * 16);
  float4 q0 = qp[0], q1 = qp[1], q2 = qp[2], q3 = qp[3];
  float qs = q0.x + q0.y + q0.z + q0.w + q1.x + q1.y + q1.z + q1.w
           + q2.x + q2.y + q2.z + q2.w + q3.x + q3.y + q3.z + q3.w;
  float qmag = sqrtf(qs + FEPS);

  int s = lane & 31;
  float dot = dotb[(size_t)m * 32 + s];
  float km = kmag[b * NS + s];
  float sc = dot / (qmag * km + FEPS);
  if (newM[b * NS + s] == 0.0f) sc = -1.0e9f;
  float myscore = sc;

  // top-8, stable (lower index wins ties), like lax.top_k
  float topv[NTOP];
  int topi[NTOP];
#pragma unroll
  for (int it = 0; it < NTOP; it++) {
    float val = myscore;
    int idx = lane & 31;
#pragma unroll
    for (int off = 32; off >= 1; off >>= 1) {
      float ov = __shfl_xor(val, off);
      int oi = __shfl_xor(idx, off);
      if (ov > val || (ov == val && oi < idx)) { val = ov; idx = oi; }
    }
    topv[it] = val;
    topi[it] = idx;
    if ((lane & 31) == idx) myscore = -3.0e38f;
  }
  float mx = topv[0];
  float w[NTOP], wsum = 0.f;
#pragma unroll
  for (int it = 0; it < NTOP; it++) { w[it] = expf(topv[it] - mx); wsum += w[it]; }
  float inv = 1.0f / wsum;

  const float2* V2p = (const float2*)newV + (size_t)b * NS * NDIM;
  float vr[8], vi[8];
#pragma unroll
  for (int j = 0; j < 8; j++) { vr[j] = 0.f; vi[j] = 0.f; }
#pragma unroll
  for (int it = 0; it < NTOP; it++) {
    float a = w[it] * inv;
    const float2* vrow = V2p + (size_t)topi[it] * NDIM;
#pragma unroll
    for (int j = 0; j < 8; j++) {
      float2 v = vrow[lane + 64 * j];
      vr[j] += a * v.x;
      vi[j] += a * v.y;
    }
  }
  float r2 = 0.f;
#pragma unroll
  for (int j = 0; j < 8; j++) r2 += vr[j] * vr[j] + vi[j] * vi[j];
#pragma unroll
  for (int off = 32; off >= 1; off >>= 1) r2 += __shfl_xor(r2, off);
  float rinv = 1.0f / sqrtf(r2 * (1.0f / 512.0f) + FEPS);

  float2* orow = (float2*)out0 + (size_t)m * NDIM;
#pragma unroll
  for (int j = 0; j < 8; j++) {
    int d = lane + 64 * j;
    float g = gain[d] * rinv;
    orow[d] = {vr[j] * g, vi[j] * g};
  }
}

extern "C" void kernel_launch(void* const* d_in, const int* in_sizes, int n_in,
                              void* d_out, int out_size, void* d_ws, size_t ws_size,
                              hipStream_t stream) {
  const float* z      = (const float*)d_in[0];
  const float* slotK  = (const float*)d_in[1];
  const float* slotV  = (const float*)d_in[2];
  const float* slotM  = (const float*)d_in[3];
  const float* Wsr    = (const float*)d_in[4];
  const float* Wsi    = (const float*)d_in[5];
  const float* sbias  = (const float*)d_in[6];
  const float* nscale = (const float*)d_in[7];
  const float* Wekr   = (const float*)d_in[8];
  const float* Weki   = (const float*)d_in[9];
  const float* Wevr   = (const float*)d_in[10];
  const float* Wevi   = (const float*)d_in[11];
  const float* Wrqr   = (const float*)d_in[12];
  const float* Wrqi   = (const float*)d_in[13];
  const float* gain   = (const float*)d_in[14];

  float* out = (float*)d_out;
  float* out0 = out;                       // (B,L,DIM,2)
  float* newK = out + 33554432;            // (B,S,DIM,2)
  float* newV = newK + 262144;
  float* newM = newV + 262144;             // (B,S)
  float* salO = newM + 256;                // (B,L)

  float* ws = (float*)d_ws;
  float* phaseb = ws;                      // 32768
  float* avgmgb = phaseb + NM;             // 32768
  float* evec   = avgmgb + NM;             // 262144
  float* emask  = evec + 262144;           // 256
  float* kmagb  = emask + 256;             // 256
  float* gvec   = kmagb + 256;             // 262144  (B,S,1024)
  float* dotb   = gvec + 262144;           // 1048576 (M,32)
  float* qpart  = dotb + 1048576;          // 524288  (M,16)
  int* estart   = (int*)(qpart + 524288);
  int* eend     = estart + 256;
  u16* BT       = (u16*)(eend + 256);      // 1024*1024 bf16 = 2 MB
  u16* Abf      = BT + 1024 * 1024;        // 32768*1024 bf16 = 64 MB

  k_wbf16<<<256, 256, 0, stream>>>(Wrqr, Wrqi, BT);
  k_phase<<<NM / 4, 256, 0, stream>>>((const float4*)z, (const float2*)Wsr,
                                      (const float2*)Wsi, phaseb, avgmgb, Abf);
  k_scan<<<NB, 256, 0, stream>>>(phaseb, avgmgb, sbias, nscale, salO, estart, eend);
  k_event<<<NB * NS, 256, 0, stream>>>((const float4*)z, salO, estart, eend,
                                       (float4*)evec, emask);
  k_kv<<<NB * NS, 256, 0, stream>>>(evec, emask, Wekr, Weki, Wevr, Wevi,
                                    slotK, slotV, slotM, newK, newV, newM, kmagb);
  k_qmag<<<2048, 256, 0, stream>>>(Abf, BT, qpart);
  k_gvec<<<NB * NS * 2, 256, 0, stream>>>(newK, Wrqr, Wrqi, gvec);
  k_dot<<<512, 256, 0, stream>>>((const float4*)z, gvec, dotb);
  k_attn2<<<NM / 4, 256, 0, stream>>>(dotb, qpart, newV, newM, kmagb, gain, out0);
}

// Round 3
// 671.877 us; speedup vs baseline: 2.3757x; 1.1492x over previous
//
#include <hip/hip_runtime.h>
#include <math.h>

#define NB 8
#define NL 4096
#define NDIM 512
#define NS 32
#define NTOP 8
#define FEPS 1e-8f
#define NM (NB*NL)   // 32768 tokens

typedef unsigned short u16;
typedef unsigned int u32;
typedef __attribute__((ext_vector_type(8))) __bf16 bf16x8;
typedef __attribute__((ext_vector_type(4))) float f32x4;

__device__ __forceinline__ u16 f2bf_rne(float f) {
  u32 u = __float_as_uint(f);
  u32 r = (u + 0x7fffu + ((u >> 16) & 1u)) >> 16;
  return (u16)r;
}

__device__ __forceinline__ void gload16(const u16* g, u16* l) {
  __builtin_amdgcn_global_load_lds(
      (const __attribute__((address_space(1))) u32*)(g),
      (__attribute__((address_space(3))) u32*)(l), 16, 0, 0);
}

// ---------------- K1: phase + avg magnitude + bf16 composite A ----------------
__global__ __launch_bounds__(256) void k_phase(
    const float4* __restrict__ z4, const float2* __restrict__ wr2,
    const float2* __restrict__ wi2, float* __restrict__ phase,
    float* __restrict__ avgmag, u16* __restrict__ A) {
  int lane = threadIdx.x & 63;
  int m = blockIdx.x * 4 + (threadIdx.x >> 6);
  const float4* row = z4 + (size_t)m * 256;   // 256 float4 per token row
  u16* arow = A + (size_t)m * 1024;
  float pr = 0.f, pi = 0.f, ms = 0.f;
#pragma unroll
  for (int j = 0; j < 4; j++) {
    int idx = lane + 64 * j;                  // covers d = 2*idx, 2*idx+1
    float4 v = row[idx];
    float2 wr = wr2[idx], wi = wi2[idx];
    pr += v.x * wr.x - v.y * wi.x + v.z * wr.y - v.w * wi.y;
    pi += v.x * wi.x + v.y * wr.x + v.z * wi.y + v.w * wr.y;
    ms += sqrtf(v.x * v.x + v.y * v.y + FEPS) + sqrtf(v.z * v.z + v.w * v.w + FEPS);
    // composite bf16 A row: [d<512]=zr, [512+d]=zi
    u32 zr_pk = ((u32)f2bf_rne(v.z) << 16) | (u32)f2bf_rne(v.x);
    u32 zi_pk = ((u32)f2bf_rne(v.w) << 16) | (u32)f2bf_rne(v.y);
    *(u32*)&arow[2 * idx] = zr_pk;
    *(u32*)&arow[512 + 2 * idx] = zi_pk;
  }
#pragma unroll
  for (int off = 32; off >= 1; off >>= 1) {
    pr += __shfl_xor(pr, off);
    pi += __shfl_xor(pi, off);
    ms += __shfl_xor(ms, off);
  }
  if (lane == 0) {
    phase[m] = sqrtf(pr * pr + pi * pi + FEPS);
    avgmag[m] = ms * (1.0f / 512.0f);
  }
}

// ---------------- K2: salience + run scan (one block per batch row) ----------------
__global__ __launch_bounds__(256) void k_scan(
    const float* __restrict__ phase, const float* __restrict__ avgmag,
    const float* __restrict__ bias_p, const float* __restrict__ ns_p,
    float* __restrict__ salO, int* __restrict__ estart, int* __restrict__ eend) {
  __shared__ float am[NL];
  __shared__ int abv[NL];
  __shared__ int cnt[256];
  int b = blockIdx.x, t = threadIdx.x;
  size_t gb = (size_t)b * NL;
  if (t < NS) { estart[b * NS + t] = -1; eend[b * NS + t] = -1; }
  for (int i = t; i < NL; i += 256) am[i] = avgmag[gb + i];
  __syncthreads();
  float bias = bias_p[0], ns = ns_p[0];
  for (int i = t; i < NL; i += 256) {
    float lm = am[i];
    if (i >= 2) lm += am[i - 2];
    if (i >= 1) lm += am[i - 1];
    if (i <= NL - 2) lm += am[i + 1];
    if (i <= NL - 3) lm += am[i + 2];
    lm *= 0.2f;
    float x = phase[gb + i] + (am[i] - lm) * ns + bias;
    float s = 1.0f / (1.0f + expf(-x));
    salO[gb + i] = s;
    abv[i] = (s > 0.5f) ? 1 : 0;
  }
  __syncthreads();
  // count starts in each thread's 16-token chunk
  int c = 0, l0 = t * 16;
  for (int j = 0; j < 16; j++) {
    int l = l0 + j;
    int a = abv[l];
    int p = (l == 0) ? 0 : abv[l - 1];
    c += (a && !p) ? 1 : 0;
  }
  cnt[t] = c;
  __syncthreads();
  for (int off = 1; off < 256; off <<= 1) {   // inclusive Hillis-Steele scan
    int v = (t >= off) ? cnt[t - off] : 0;
    __syncthreads();
    cnt[t] += v;
    __syncthreads();
  }
  c = (t > 0) ? cnt[t - 1] : 0;
  for (int j = 0; j < 16; j++) {
    int l = l0 + j;
    int a = abv[l];
    int p = (l == 0) ? 0 : abv[l - 1];
    int st = (a && !p) ? 1 : 0;
    c += st;
    int ev = c - 1;
    if (a && ev >= 0 && ev < NS) {
      if (st) estart[b * NS + ev] = l;
      int nxt = (l == NL - 1) ? 0 : abv[l + 1];
      if (!nxt) eend[b * NS + ev] = l + 1;
    }
  }
}

// ---------------- K3: event accumulation (one block per (b,s)) ----------------
__global__ __launch_bounds__(256) void k_event(
    const float4* __restrict__ z4, const float* __restrict__ salO,
    const int* __restrict__ estart, const int* __restrict__ eend,
    float4* __restrict__ evec4, float* __restrict__ emask) {
  int i = blockIdx.x;            // b*NS + s
  int b = i >> 5;
  int t = threadIdx.x;
  int st = estart[i];
  int en = (st >= 0) ? eend[i] : 0;
  if (st < 0) st = 0;
  float4 acc = {0.f, 0.f, 0.f, 0.f};
  float den = 0.f;
  for (int l = st; l < en; l++) {
    float w = salO[(size_t)b * NL + l];
    float4 v = z4[((size_t)b * NL + l) * 256 + t];
    acc.x += w * v.x; acc.y += w * v.y; acc.z += w * v.z; acc.w += w * v.w;
    den += w;
  }
  float inv = 1.0f / fmaxf(den, FEPS);
  float4 o = {acc.x * inv, acc.y * inv, acc.z * inv, acc.w * inv};
  evec4[(size_t)i * 256 + t] = o;
  if (t == 0) emask[i] = (den > 0.f) ? 1.0f : 0.0f;
}

// ---------------- K4: event keys/values + blend + new_mask ----------------
// 512 blocks: (32 event-octets) x (matsel 2) x (dq 8 of 64 cols).
// Each wave owns 2 events -> ev LDS reads are 64-lane broadcasts.
__global__ __launch_bounds__(256) void k_kv(
    const float* __restrict__ evec, const float* __restrict__ emask,
    const float* __restrict__ Wekr, const float* __restrict__ Weki,
    const float* __restrict__ Wevr, const float* __restrict__ Wevi,
    const float* __restrict__ slotK, const float* __restrict__ slotV,
    const float* __restrict__ slotM, float* __restrict__ newK,
    float* __restrict__ newV, float* __restrict__ newM) {
  __shared__ float ev[8][1024];
  __shared__ float em[8];
  int blk = blockIdx.x;
  int eg = blk >> 4;          // 32 groups of 8 events
  int q  = blk & 15;
  int matsel = q >> 3, dq = q & 7;
  int i0 = eg * 8;
  int t = threadIdx.x;
  {
    const float4* src = (const float4*)(evec + (size_t)i0 * 1024);
    float4* dst = (float4*)&ev[0][0];
    for (int j = t; j < 2048; j += 256) dst[j] = src[j];
  }
  if (t < 8) em[t] = emask[i0 + t];
  __syncthreads();
  int dl = t & 63, eh = t >> 6;      // eh constant per wave
  int d = dq * 64 + dl;
  int e0 = eh * 2, e1 = e0 + 1;
  const float* Wr = matsel ? Wevr : Wekr;
  const float* Wi = matsel ? Wevi : Weki;
  const float* wrp = Wr + d;
  const float* wip = Wi + d;
  const float2* ep0 = (const float2*)ev[e0];
  const float2* ep1 = (const float2*)ev[e1];
  float ar0 = 0.f, ai0 = 0.f, ar1 = 0.f, ai1 = 0.f;
#pragma unroll 8
  for (int k = 0; k < 512; k++) {
    float wr = wrp[(size_t)k * 512];
    float wi = wip[(size_t)k * 512];
    float2 x0 = ep0[k], x1 = ep1[k];
    ar0 += x0.x * wr - x0.y * wi; ai0 += x0.x * wi + x0.y * wr;
    ar1 += x1.x * wr - x1.y * wi; ai1 += x1.x * wi + x1.y * wr;
  }
  int ii0 = i0 + e0, ii1 = i0 + e1;
  float m0 = em[e0], m1 = em[e1];
  const float2* slot = (const float2*)(matsel ? slotV : slotK);
  float2* outp = (float2*)(matsel ? newV : newK);
  float2 sl0 = slot[(size_t)ii0 * NDIM + d];
  float2 sl1 = slot[(size_t)ii1 * NDIM + d];
  float2 o0, o1;
  o0.x = (m0 > 0.f) ? ar0 : sl0.x; o0.y = (m0 > 0.f) ? ai0 : sl0.y;
  o1.x = (m1 > 0.f) ? ar1 : sl1.x; o1.y = (m1 > 0.f) ? ai1 : sl1.y;
  outp[(size_t)ii0 * NDIM + d] = o0;
  outp[(size_t)ii1 * NDIM + d] = o1;
  if (matsel == 0 && dq == 0 && t < 8)
    newM[i0 + t] = fminf(slotM[i0 + t] + em[t], 1.0f);
}

// ---------------- K5a: build transposed composite B in bf16 ----------------
// BT[n][k] = Bcomp[k][n], Bcomp = [[Wr, Wi], [-Wi, Wr]]  (1024x1024)
__global__ __launch_bounds__(256) void k_wbf16(
    const float* __restrict__ Wr, const float* __restrict__ Wi,
    u16* __restrict__ BT) {
  __shared__ float tile[64][65];
  int bx = blockIdx.x & 15;   // k-tile
  int by = blockIdx.x >> 4;   // n-tile
  int k0 = bx * 64, n0 = by * 64;
  int t = threadIdx.x;
  int c = t & 63, r0 = t >> 6;
  const float* src;
  float sgn = 1.f;
  int kk0 = k0 & 511, nn0 = n0 & 511;
  if (k0 < 512) {
    src = (n0 < 512) ? Wr : Wi;
  } else {
    if (n0 < 512) { src = Wi; sgn = -1.f; }
    else          { src = Wr; }
  }
  for (int j = r0; j < 64; j += 4)
    tile[j][c] = sgn * src[(size_t)(kk0 + j) * 512 + nn0 + c];
  __syncthreads();
  for (int j = r0; j < 64; j += 4) {
    float v = tile[c][j];   // = Bcomp[k0+c][n0+j]
    BT[(size_t)(n0 + j) * 1024 + k0 + c] = f2bf_rne(v);
  }
}

// ---------------- K5b: qmag via bf16 MFMA GEMM, m97 structure ----------------
// A (M x 1024 bf16, pre-converted), BT (1024 x 1024 bf16, [n][k])
// output: qpart[m][nt16] = partial row sums of Q^2 (16 partials per row)
__global__ __launch_bounds__(256) void k_qmag(
    const u16* __restrict__ A, const u16* __restrict__ BT,
    float* __restrict__ qpart) {
  __shared__ __align__(16) u16 As[128 * 32];
  __shared__ __align__(16) u16 Bs[128 * 32];
  int bid = blockIdx.x;
  int work = (bid & 7) * 256 + (bid >> 3);   // XCD swizzle (2048 % 8 == 0)
  int mt = work >> 3, nt = work & 7;
  int m0 = mt * 128, n0 = nt * 128;
  int t = threadIdx.x;
  int lane = t & 63, w = t >> 6;
  int wr = w >> 1, wc = w & 1;               // wave's 64x64 quadrant
  int lrow = lane & 15, kg = lane >> 4;
  int grow = w * 16 + (lane >> 2);
  int gcol = (lane & 3) * 8;
  const u16* gA = A  + (size_t)(m0 + grow) * 1024 + gcol;
  const u16* gB = BT + (size_t)(n0 + grow) * 1024 + gcol;
  u16* lA = As + w * 512;   // element offset: byte w*1024
  u16* lB = Bs + w * 512;

  f32x4 acc[4][4];
#pragma unroll
  for (int i = 0; i < 4; i++)
#pragma unroll
    for (int j = 0; j < 4; j++)
#pragma unroll
      for (int r = 0; r < 4; r++) acc[i][j][r] = 0.f;

  for (int kt = 0; kt < 1024; kt += 32) {
    gload16(gA + kt, lA);
    gload16(gA + 64 * 1024 + kt, lA + 2048);
    gload16(gB + kt, lB);
    gload16(gB + 64 * 1024 + kt, lB + 2048);
    __syncthreads();
    bf16x8 af[4], bfr[4];
#pragma unroll
    for (int i = 0; i < 4; i++)
      af[i] = *(const bf16x8*)&As[(wr * 64 + i * 16 + lrow) * 32 + kg * 8];
#pragma unroll
    for (int j = 0; j < 4; j++)
      bfr[j] = *(const bf16x8*)&Bs[(wc * 64 + j * 16 + lrow) * 32 + kg * 8];
#pragma unroll
    for (int i = 0; i < 4; i++)
#pragma unroll
      for (int j = 0; j < 4; j++)
        acc[i][j] = __builtin_amdgcn_mfma_f32_16x16x32_bf16(af[i], bfr[j], acc[i][j], 0, 0, 0);
    __syncthreads();
  }
  // epilogue: sum of squares over this wave's 64 cols; C/D: col=lane&15, row=kg*4+r
#pragma unroll
  for (int i = 0; i < 4; i++)
#pragma unroll
    for (int r = 0; r < 4; r++) {
      float s = 0.f;
#pragma unroll
      for (int j = 0; j < 4; j++) { float v = acc[i][j][r]; s += v * v; }
      s += __shfl_xor(s, 1); s += __shfl_xor(s, 2);
      s += __shfl_xor(s, 4); s += __shfl_xor(s, 8);
      if (lrow == 0)
        qpart[(size_t)(m0 + wr * 64 + i * 16 + kg * 4 + r) * 16 + nt * 2 + wc] = s;
    }
}

// ---------------- K6: g[b][s] = Bcomp @ khat + kmag  (fp32, two blocks per (b,s)) ----------------
__global__ __launch_bounds__(256) void k_gvec(
    const float* __restrict__ newK, const float* __restrict__ Wr,
    const float* __restrict__ Wi, float* __restrict__ g,
    float* __restrict__ kmag) {
  __shared__ float kr[512], ki[512];
  __shared__ float red[256];
  int blk = blockIdx.x;
  int i = blk >> 1, h = blk & 1;
  int t = threadIdx.x;
  const float2* krow = (const float2*)newK + (size_t)i * 512;
  for (int j = t; j < 512; j += 256) { float2 v = krow[j]; kr[j] = v.x; ki[j] = v.y; }
  __syncthreads();
  if (h == 0) {   // block-uniform branch: kmag reduction
    red[t] = kr[t] * kr[t] + ki[t] * ki[t]
           + kr[t + 256] * kr[t + 256] + ki[t + 256] * ki[t + 256];
    __syncthreads();
    for (int off = 128; off >= 1; off >>= 1) {
      if (t < off) red[t] += red[t + off];
      __syncthreads();
    }
    if (t == 0) kmag[i] = sqrtf(red[0] + FEPS);
  }
  int j = t + h * 256;   // output row
  float glo = 0, ghi = 0;
  const float4* wr0 = (const float4*)(Wr + (size_t)j * 512);
  const float4* wi0 = (const float4*)(Wi + (size_t)j * 512);
  const float4* kr4 = (const float4*)kr;
  const float4* ki4 = (const float4*)ki;
  for (int n4 = 0; n4 < 128; n4++) {
    float4 a = wr0[n4], b = wi0[n4];
    float4 kk = kr4[n4], qq = ki4[n4];
    glo += a.x * kk.x + b.x * qq.x + a.y * kk.y + b.y * qq.y
         + a.z * kk.z + b.z * qq.z + a.w * kk.w + b.w * qq.w;
    ghi += a.x * qq.x - b.x * kk.x + a.y * qq.y - b.y * kk.y
         + a.z * qq.z - b.z * kk.z + a.w * qq.w - b.w * kk.w;
  }
  float* go = g + (size_t)i * 1024;
  go[j] = glo;
  go[512 + j] = ghi;
}

// ---------------- K7: dot[m][s] = Zc[m] . g[b][s]  (fp32, LDS-staged g) ----------------
__global__ __launch_bounds__(256) void k_dot(
    const float4* __restrict__ z4, const float* __restrict__ g,
    float* __restrict__ dotb) {
  __shared__ float gs[16 * 1024];    // 64 KB: 16 slots per pass
  int blk = blockIdx.x;              // 512 blocks: 64 tokens each
  int b = blk >> 6, chunk = blk & 63;
  int t = threadIdx.x, lane = t & 63, w = t >> 6;
  int mbase = b * 4096 + chunk * 64 + w * 16;
  for (int p = 0; p < 2; p++) {
    __syncthreads();
    {
      const float4* gsrc = (const float4*)(g + (size_t)b * 32768 + p * 16384);
      float4* gd = (float4*)gs;
      for (int j = t; j < 4096; j += 256) gd[j] = gsrc[j];
    }
    __syncthreads();
    for (int it = 0; it < 4; it++) {
      int m = mbase + it * 4;
      float4 zr0[4], zr1[4], zr2[4], zr3[4];
#pragma unroll
      for (int jj = 0; jj < 4; jj++) {
        zr0[jj] = z4[(size_t)(m + 0) * 256 + lane + 64 * jj];
        zr1[jj] = z4[(size_t)(m + 1) * 256 + lane + 64 * jj];
        zr2[jj] = z4[(size_t)(m + 2) * 256 + lane + 64 * jj];
        zr3[jj] = z4[(size_t)(m + 3) * 256 + lane + 64 * jj];
      }
      float myd0 = 0, myd1 = 0, myd2 = 0, myd3 = 0;
      for (int s = 0; s < 16; s++) {
        float p0 = 0, p1 = 0, p2 = 0, p3 = 0;
        const float2* gl = (const float2*)(gs + s * 1024);
#pragma unroll
        for (int jj = 0; jj < 4; jj++) {
          int idx = lane + 64 * jj;
          float2 lo = gl[idx], hi = gl[256 + idx];
          p0 += zr0[jj].x * lo.x + zr0[jj].z * lo.y + zr0[jj].y * hi.x + zr0[jj].w * hi.y;
          p1 += zr1[jj].x * lo.x + zr1[jj].z * lo.y + zr1[jj].y * hi.x + zr1[jj].w * hi.y;
          p2 += zr2[jj].x * lo.x + zr2[jj].z * lo.y + zr2[jj].y * hi.x + zr2[jj].w * hi.y;
          p3 += zr3[jj].x * lo.x + zr3[jj].z * lo.y + zr3[jj].y * hi.x + zr3[jj].w * hi.y;
        }
#pragma unroll
        for (int off = 32; off >= 1; off >>= 1) {
          p0 += __shfl_xor(p0, off);
          p1 += __shfl_xor(p1, off);
          p2 += __shfl_xor(p2, off);
          p3 += __shfl_xor(p3, off);
        }
        if (lane == s) { myd0 = p0; myd1 = p1; myd2 = p2; myd3 = p3; }
      }
      if (lane < 16) {
        int sidx = p * 16 + lane;
        dotb[(size_t)(m + 0) * 32 + sidx] = myd0;
        dotb[(size_t)(m + 1) * 32 + sidx] = myd1;
        dotb[(size_t)(m + 2) * 32 + sidx] = myd2;
        dotb[(size_t)(m + 3) * 32 + sidx] = myd3;
      }
    }
  }
}

// ---------------- K8: attention tail, one wave per token ----------------
__global__ __launch_bounds__(256) void k_attn2(
    const float* __restrict__ dotb, const float* __restrict__ qpart,
    const float* __restrict__ newV, const float* __restrict__ newM,
    const float* __restrict__ kmag, const float* __restrict__ gain,
    float* __restrict__ out0) {
  int lane = threadIdx.x & 63;
  int m = blockIdx.x * 4 + (threadIdx.x >> 6);
  int b = m >> 12;
  const float4* qp = (const float4*)(qpart + (size_t)m * 16);
  float4 q0 = qp[0], q1 = qp[1], q2 = qp[2], q3 = qp[3];
  float qs = q0.x + q0.y + q0.z + q0.w + q1.x + q1.y + q1.z + q1.w
           + q2.x + q2.y + q2.z + q2.w + q3.x + q3.y + q3.z + q3.w;
  float qmag = sqrtf(qs + FEPS);

  int s = lane & 31;
  float dot = dotb[(size_t)m * 32 + s];
  float km = kmag[b * NS + s];
  float sc = dot / (qmag * km + FEPS);
  if (newM[b * NS + s] == 0.0f) sc = -1.0e9f;
  float myscore = sc;

  // top-8, stable (lower index wins ties), like lax.top_k
  float topv[NTOP];
  int topi[NTOP];
#pragma unroll
  for (int it = 0; it < NTOP; it++) {
    float val = myscore;
    int idx = lane & 31;
#pragma unroll
    for (int off = 32; off >= 1; off >>= 1) {
      float ov = __shfl_xor(val, off);
      int oi = __shfl_xor(idx, off);
      if (ov > val || (ov == val && oi < idx)) { val = ov; idx = oi; }
    }
    topv[it] = val;
    topi[it] = idx;
    if ((lane & 31) == idx) myscore = -3.0e38f;
  }
  float mx = topv[0];
  float w[NTOP], wsum = 0.f;
#pragma unroll
  for (int it = 0; it < NTOP; it++) { w[it] = expf(topv[it] - mx); wsum += w[it]; }
  float inv = 1.0f / wsum;

  const float2* V2p = (const float2*)newV + (size_t)b * NS * NDIM;
  float vr[8], vi[8];
#pragma unroll
  for (int j = 0; j < 8; j++) { vr[j] = 0.f; vi[j] = 0.f; }
#pragma unroll
  for (int it = 0; it < NTOP; it++) {
    float a = w[it] * inv;
    const float2* vrow = V2p + (size_t)topi[it] * NDIM;
#pragma unroll
    for (int j = 0; j < 8; j++) {
      float2 v = vrow[lane + 64 * j];
      vr[j] += a * v.x;
      vi[j] += a * v.y;
    }
  }
  float r2 = 0.f;
#pragma unroll
  for (int j = 0; j < 8; j++) r2 += vr[j] * vr[j] + vi[j] * vi[j];
#pragma unroll
  for (int off = 32; off >= 1; off >>= 1) r2 += __shfl_xor(r2, off);
  float rinv = 1.0f / sqrtf(r2 * (1.0f / 512.0f) + FEPS);

  float2* orow = (float2*)out0 + (size_t)m * NDIM;
#pragma unroll
  for (int j = 0; j < 8; j++) {
    int d = lane + 64 * j;
    float g = gain[d] * rinv;
    orow[d] = {vr[j] * g, vi[j] * g};
  }
}

extern "C" void kernel_launch(void* const* d_in, const int* in_sizes, int n_in,
                              void* d_out, int out_size, void* d_ws, size_t ws_size,
                              hipStream_t stream) {
  const float* z      = (const float*)d_in[0];
  const float* slotK  = (const float*)d_in[1];
  const float* slotV  = (const float*)d_in[2];
  const float* slotM  = (const float*)d_in[3];
  const float* Wsr    = (const float*)d_in[4];
  const float* Wsi    = (const float*)d_in[5];
  const float* sbias  = (const float*)d_in[6];
  const float* nscale = (const float*)d_in[7];
  const float* Wekr   = (const float*)d_in[8];
  const float* Weki   = (const float*)d_in[9];
  const float* Wevr   = (const float*)d_in[10];
  const float* Wevi   = (const float*)d_in[11];
  const float* Wrqr   = (const float*)d_in[12];
  const float* Wrqi   = (const float*)d_in[13];
  const float* gain   = (const float*)d_in[14];

  float* out = (float*)d_out;
  float* out0 = out;                       // (B,L,DIM,2)
  float* newK = out + 33554432;            // (B,S,DIM,2)
  float* newV = newK + 262144;
  float* newM = newV + 262144;             // (B,S)
  float* salO = newM + 256;                // (B,L)

  float* ws = (float*)d_ws;
  float* phaseb = ws;                      // 32768
  float* avgmgb = phaseb + NM;             // 32768
  float* evec   = avgmgb + NM;             // 262144
  float* emask  = evec + 262144;           // 256
  float* kmagb  = emask + 256;             // 256
  float* gvec   = kmagb + 256;             // 262144  (B,S,1024)
  float* dotb   = gvec + 262144;           // 1048576 (M,32)
  float* qpart  = dotb + 1048576;          // 524288  (M,16)
  int* estart   = (int*)(qpart + 524288);
  int* eend     = estart + 256;
  u16* BT       = (u16*)(eend + 256);      // 1024*1024 bf16 = 2 MB
  u16* Abf      = BT + 1024 * 1024;        // 32768*1024 bf16 = 64 MB

  k_wbf16<<<256, 256, 0, stream>>>(Wrqr, Wrqi, BT);
  k_phase<<<NM / 4, 256, 0, stream>>>((const float4*)z, (const float2*)Wsr,
                                      (const float2*)Wsi, phaseb, avgmgb, Abf);
  k_scan<<<NB, 256, 0, stream>>>(phaseb, avgmgb, sbias, nscale, salO, estart, eend);
  k_event<<<NB * NS, 256, 0, stream>>>((const float4*)z, salO, estart, eend,
                                       (float4*)evec, emask);
  k_kv<<<512, 256, 0, stream>>>(evec, emask, Wekr, Weki, Wevr, Wevi,
                                slotK, slotV, slotM, newK, newV, newM);
  k_qmag<<<2048, 256, 0, stream>>>(Abf, BT, qpart);
  k_gvec<<<NB * NS * 2, 256, 0, stream>>>(newK, Wrqr, Wrqi, gvec, kmagb);
  k_dot<<<512, 256, 0, stream>>>((const float4*)z, gvec, dotb);
  k_attn2<<<NM / 4, 256, 0, stream>>>(dotb, qpart, newV, newM, kmagb, gain, out0);
}